// Round 1
// baseline (1052.007 us; speedup 1.0000x reference)
//
#include <hip/hip_runtime.h>
#include <math.h>

#define NTOK 2048
#define DDIM 768
#define IDIM 384
#define NEXP 16
#define TOPK 2
#define TT 8            // tokens per FFN block
#define D4 (DDIM/4)     // 192
#define I4 (IDIM/4)     // 96
#define HPAD 97         // h tile stride in float4 (96 + 1 pad)

// ---------------- workspace layout (bytes) ----------------
// 0     : counts[16]  (int)
// 64    : cursor[16]  (int)
// 128   : offsets[17] (int)
// 256   : p_sum[16]   (float)
// 512   : topk_i[N*2] (int)    16384
// 16896 : topk_w[N*2] (float)  16384
// 33280 : perm_t[N*2] (int)    16384
// 49664 : perm_w[N*2] (float)  16384
// total 66048

__global__ __launch_bounds__(64) void init_kernel(int* counts, int* cursor,
                                                  int* offs, float* p_sum) {
    int t = threadIdx.x;
    if (t < 16) { counts[t] = 0; cursor[t] = 0; p_sum[t] = 0.f; }
    if (t < 17) offs[t] = 0;
}

__global__ __launch_bounds__(256) void gate_kernel(
    const float* __restrict__ x, const float* __restrict__ gate_w,
    int* __restrict__ topk_i, float* __restrict__ topk_w,
    int* __restrict__ counts, float* __restrict__ p_sum) {
    __shared__ float p_blk[16];
    __shared__ int   c_blk[16];
    int tid = threadIdx.x;
    if (tid < 16) { p_blk[tid] = 0.f; c_blk[tid] = 0; }
    __syncthreads();

    int wave = tid >> 6, lane = tid & 63;
    int n = blockIdx.x * 4 + wave;   // grid = 512 -> n < 2048
    int e = lane >> 2, q = lane & 3;
    const float4* xr = (const float4*)(x + (size_t)n * DDIM);
    const float4* wr = (const float4*)(gate_w + (size_t)e * DDIM);
    float s = 0.f;
    #pragma unroll 4
    for (int k = q * 48; k < q * 48 + 48; ++k) {
        float4 a = xr[k], b = wr[k];
        s += a.x * b.x + a.y * b.y + a.z * b.z + a.w * b.w;
    }
    s += __shfl_xor(s, 1);
    s += __shfl_xor(s, 2);
    float logit = s * 2.5f;          // lane 4*j holds logit of expert j

    float l[16];
    #pragma unroll
    for (int j = 0; j < 16; ++j) l[j] = __shfl(logit, j * 4);

    float m = l[0];
    #pragma unroll
    for (int j = 1; j < 16; ++j) m = fmaxf(m, l[j]);
    float sum = 0.f, sc[16];
    #pragma unroll
    for (int j = 0; j < 16; ++j) { sc[j] = __expf(l[j] - m); sum += sc[j]; }
    float inv = 1.f / sum;
    #pragma unroll
    for (int j = 0; j < 16; ++j) sc[j] *= inv;

    // top-2, first-index tie-break (matches lax.top_k)
    float b0 = -1.f; int i0 = 0;
    #pragma unroll
    for (int j = 0; j < 16; ++j) if (sc[j] > b0) { b0 = sc[j]; i0 = j; }
    float b1 = -1.f; int i1 = 0;
    #pragma unroll
    for (int j = 0; j < 16; ++j) if (j != i0 && sc[j] > b1) { b1 = sc[j]; i1 = j; }
    float rs = 1.f / (b0 + b1);
    float w0 = b0 * rs, w1 = b1 * rs;

    if (lane == 0) {
        topk_i[n * 2] = i0; topk_i[n * 2 + 1] = i1;
        topk_w[n * 2] = w0; topk_w[n * 2 + 1] = w1;
        atomicAdd(&c_blk[i0], 1); atomicAdd(&c_blk[i1], 1);
        #pragma unroll
        for (int j = 0; j < 16; ++j) atomicAdd(&p_blk[j], sc[j]);
    }
    __syncthreads();
    if (tid < 16) {
        atomicAdd(&p_sum[tid], p_blk[tid]);
        atomicAdd(&counts[tid], c_blk[tid]);
    }
}

__global__ __launch_bounds__(64) void offsets_kernel(const int* counts, int* offs) {
    if (threadIdx.x == 0) {
        int acc = 0;
        for (int e = 0; e < 16; ++e) { offs[e] = acc; acc += counts[e]; }
        offs[16] = acc;
    }
}

__global__ __launch_bounds__(256) void scatter_kernel(
    const int* __restrict__ topk_i, const float* __restrict__ topk_w,
    const int* __restrict__ offs, int* __restrict__ cursor,
    int* __restrict__ perm_t, float* __restrict__ perm_w) {
    int n = blockIdx.x * 256 + threadIdx.x;
    if (n >= NTOK) return;
    #pragma unroll
    for (int k = 0; k < 2; ++k) {
        int e = topk_i[n * 2 + k];
        int pos = atomicAdd(&cursor[e], 1);
        int s = offs[e] + pos;
        perm_t[s] = n;
        perm_w[s] = topk_w[n * 2 + k];
    }
}

// Fused SwiGLU FFN block: TT tokens, full I intermediate, full D output.
// shared_mode=1: identity token list, weight 1, plain store (initializes out).
// shared_mode=0: expert blockIdx.y, compacted token list, atomicAdd.
__global__ __launch_bounds__(384) void ffn_kernel(
    const float* __restrict__ x,
    const float* __restrict__ gw, const float* __restrict__ uw,
    const float* __restrict__ dw,
    const int* __restrict__ perm_t, const float* __restrict__ perm_w,
    const int* __restrict__ offs, const int* __restrict__ counts,
    float* __restrict__ out, int shared_mode) {
    __shared__ float4 xl4[TT * D4];   // 24 KB
    __shared__ float4 hl4[TT * HPAD]; // 12.1 KB
    __shared__ int   s_tok[TT];
    __shared__ float s_w[TT];

    int tid = threadIdx.x;
    int tileStart = blockIdx.x * TT;

    if (!shared_mode) {
        int e = blockIdx.y;
        int cnt = counts[e];
        if (tileStart >= cnt) return;
        gw += (size_t)e * (IDIM * DDIM);
        uw += (size_t)e * (IDIM * DDIM);
        dw += (size_t)e * (DDIM * IDIM);
        int base = offs[e];
        if (tid < TT) {
            int slot = tileStart + tid;
            if (slot < cnt) { s_tok[tid] = perm_t[base + slot]; s_w[tid] = perm_w[base + slot]; }
            else            { s_tok[tid] = 0;                   s_w[tid] = 0.f; }
        }
    } else {
        if (tid < TT) { s_tok[tid] = tileStart + tid; s_w[tid] = 1.f; }
    }
    __syncthreads();

    // stage x rows (gathered) into LDS
    const float4* x4 = (const float4*)x;
    for (int idx = tid; idx < TT * D4; idx += 384) {
        int t = idx / D4, c = idx - t * D4;
        xl4[idx] = x4[(size_t)s_tok[t] * D4 + c];
    }
    __syncthreads();

    // phase 1: h[t][i] = silu(x.g_w) * (x.u_w), i = tid (384 threads = IDIM)
    float g[TT], u[TT];
    #pragma unroll
    for (int t = 0; t < TT; ++t) { g[t] = 0.f; u[t] = 0.f; }
    const float4* gw4 = (const float4*)(gw + (size_t)tid * DDIM);
    const float4* uw4 = (const float4*)(uw + (size_t)tid * DDIM);
    for (int k = 0; k < D4; ++k) {
        float4 a = gw4[k], b = uw4[k];
        #pragma unroll
        for (int t = 0; t < TT; ++t) {
            float4 xv = xl4[t * D4 + k];   // wave-uniform broadcast
            g[t] += a.x * xv.x + a.y * xv.y + a.z * xv.z + a.w * xv.w;
            u[t] += b.x * xv.x + b.y * xv.y + b.z * xv.z + b.w * xv.w;
        }
    }
    float* h_s = (float*)hl4;
    #pragma unroll
    for (int t = 0; t < TT; ++t) {
        float gv = g[t];
        float hv = gv / (1.f + __expf(-gv)) * u[t];
        h_s[t * (HPAD * 4) + tid] = hv;
    }
    __syncthreads();

    // phase 2: out[t][d] = sum_i h[t][i] * dw[d][i]; d = tid, tid+384
    float acc0[TT], acc1[TT];
    #pragma unroll
    for (int t = 0; t < TT; ++t) { acc0[t] = 0.f; acc1[t] = 0.f; }
    const float4* dwa = (const float4*)(dw + (size_t)tid * IDIM);
    const float4* dwb = (const float4*)(dw + (size_t)(tid + 384) * IDIM);
    for (int i = 0; i < I4; ++i) {
        float4 wa = dwa[i], wb = dwb[i];
        #pragma unroll
        for (int t = 0; t < TT; ++t) {
            float4 hv = hl4[t * HPAD + i];   // wave-uniform broadcast
            acc0[t] += wa.x * hv.x + wa.y * hv.y + wa.z * hv.z + wa.w * hv.w;
            acc1[t] += wb.x * hv.x + wb.y * hv.y + wb.z * hv.z + wb.w * hv.w;
        }
    }
    #pragma unroll
    for (int t = 0; t < TT; ++t) {
        int n = s_tok[t];
        float w = s_w[t];
        float* o0 = out + (size_t)n * DDIM + tid;
        if (shared_mode) {
            o0[0]   = acc0[t];
            o0[384] = acc1[t];
        } else if (w != 0.f) {
            atomicAdd(&o0[0],   w * acc0[t]);
            atomicAdd(&o0[384], w * acc1[t]);
        }
    }
}

__global__ __launch_bounds__(64) void aux_kernel(const int* counts, const float* p_sum,
                                                 float* out_aux) {
    if (threadIdx.x == 0) {
        float a = 0.f;
        for (int e = 0; e < 16; ++e) a += (float)counts[e] * p_sum[e];
        out_aux[0] = a * 16.f / ((float)NTOK * (float)NTOK);
    }
}

extern "C" void kernel_launch(void* const* d_in, const int* in_sizes, int n_in,
                              void* d_out, int out_size, void* d_ws, size_t ws_size,
                              hipStream_t stream) {
    const float* x      = (const float*)d_in[0];
    const float* gate_w = (const float*)d_in[1];
    const float* sg_w   = (const float*)d_in[2];
    const float* su_w   = (const float*)d_in[3];
    const float* sd_w   = (const float*)d_in[4];
    const float* rg_w   = (const float*)d_in[5];
    const float* ru_w   = (const float*)d_in[6];
    const float* rd_w   = (const float*)d_in[7];
    float* out = (float*)d_out;

    char* ws = (char*)d_ws;
    int*   counts = (int*)(ws + 0);
    int*   cursor = (int*)(ws + 64);
    int*   offs   = (int*)(ws + 128);
    float* p_sum  = (float*)(ws + 256);
    int*   topk_i = (int*)(ws + 512);
    float* topk_w = (float*)(ws + 16896);
    int*   perm_t = (int*)(ws + 33280);
    float* perm_w = (float*)(ws + 49664);

    init_kernel<<<1, 64, 0, stream>>>(counts, cursor, offs, p_sum);
    gate_kernel<<<NTOK / 4, 256, 0, stream>>>(x, gate_w, topk_i, topk_w, counts, p_sum);
    offsets_kernel<<<1, 64, 0, stream>>>(counts, offs);
    scatter_kernel<<<NTOK / 256, 256, 0, stream>>>(topk_i, topk_w, offs, cursor, perm_t, perm_w);
    // shared expert: initializes all of out
    ffn_kernel<<<dim3(NTOK / TT, 1), 384, 0, stream>>>(
        x, sg_w, su_w, sd_w, nullptr, nullptr, nullptr, nullptr, out, 1);
    // routed experts: atomicAdd on top
    ffn_kernel<<<dim3(NTOK / TT, NEXP), 384, 0, stream>>>(
        x, rg_w, ru_w, rd_w, perm_t, perm_w, offs, counts, out, 0);
    aux_kernel<<<1, 64, 0, stream>>>(counts, p_sum, out + (size_t)NTOK * DDIM);
}

// Round 2
// 377.681 us; speedup vs baseline: 2.7854x; 2.7854x over previous
//
#include <hip/hip_runtime.h>
#include <math.h>

#define NTOK 2048
#define DDIM 768
#define IDIM 384
#define NEXP 16
#define MT   32          // tokens per FFN tile
#define XS_LD 776        // 768 + 8 pad (ushorts)
#define HS_LD 392        // 384 + 8 pad (ushorts)

typedef __attribute__((ext_vector_type(8))) short short8;   // 8 bf16 = 4 VGPR
typedef __attribute__((ext_vector_type(4))) float f32x4;    // MFMA C/D

__device__ __forceinline__ unsigned short f2bf(float f) {
    unsigned int u = __float_as_uint(f);
    unsigned int r = (u + 0x7fffu + ((u >> 16) & 1u)) >> 16;   // RNE
    return (unsigned short)r;
}

// ---------------- workspace layout (bytes) ----------------
// 0      counts[16] | 64 cursor[16] | 128 offs[17] | 256 p_sum[16]
// 512    topk_i[N*2] int   | 16896 topk_w[N*2] f32
// 33280  perm_t[N*2] int   | 49664 perm_w[N*2] f32
// 1 MB.. bf16 weights: wsg, wsu, wsd (589,824 B each), wrg, wru, wrd (9,437,184 B each)
#define WS_WSG 1048576u
#define WS_WSU (WS_WSG + 589824u)
#define WS_WSD (WS_WSU + 589824u)
#define WS_WRG (WS_WSD + 589824u)
#define WS_WRU (WS_WRG + 9437184u)
#define WS_WRD (WS_WRU + 9437184u)
// end = 31,129,600 + 9,437,184 = 40,566,784 ... (wrd ends at WS_WRD + 9437184)

__global__ __launch_bounds__(64) void init_kernel(int* counts, int* cursor,
                                                  int* offs, float* p_sum) {
    int t = threadIdx.x;
    if (t < 16) { counts[t] = 0; cursor[t] = 0; p_sum[t] = 0.f; }
    if (t < 17) offs[t] = 0;
}

// fp32 -> bf16 conversion, 3 equally-sized tensors, float4-vectorized grid-stride
__global__ __launch_bounds__(256) void conv3_kernel(
    const float* __restrict__ s0, const float* __restrict__ s1, const float* __restrict__ s2,
    unsigned short* __restrict__ d0, unsigned short* __restrict__ d1,
    unsigned short* __restrict__ d2, int n4) {
    const float* s = (blockIdx.y == 0) ? s0 : (blockIdx.y == 1) ? s1 : s2;
    unsigned short* d = (blockIdx.y == 0) ? d0 : (blockIdx.y == 1) ? d1 : d2;
    int stride = gridDim.x * 256;
    for (int i = blockIdx.x * 256 + threadIdx.x; i < n4; i += stride) {
        float4 v = ((const float4*)s)[i];
        ushort4 b;
        b.x = f2bf(v.x); b.y = f2bf(v.y); b.z = f2bf(v.z); b.w = f2bf(v.w);
        ((ushort4*)d)[i] = b;
    }
}

__global__ __launch_bounds__(256) void gate_kernel(
    const float* __restrict__ x, const float* __restrict__ gate_w,
    int* __restrict__ topk_i, float* __restrict__ topk_w,
    int* __restrict__ counts, float* __restrict__ p_sum) {
    __shared__ float p_blk[16];
    __shared__ int   c_blk[16];
    int tid = threadIdx.x;
    if (tid < 16) { p_blk[tid] = 0.f; c_blk[tid] = 0; }
    __syncthreads();

    int wave = tid >> 6, lane = tid & 63;
    int n = blockIdx.x * 4 + wave;
    int e = lane >> 2, q = lane & 3;
    const float4* xr = (const float4*)(x + (size_t)n * DDIM);
    const float4* wr = (const float4*)(gate_w + (size_t)e * DDIM);
    float s = 0.f;
    #pragma unroll 4
    for (int k = q * 48; k < q * 48 + 48; ++k) {
        float4 a = xr[k], b = wr[k];
        s += a.x * b.x + a.y * b.y + a.z * b.z + a.w * b.w;
    }
    s += __shfl_xor(s, 1);
    s += __shfl_xor(s, 2);
    float logit = s * 2.5f;

    float l[16];
    #pragma unroll
    for (int j = 0; j < 16; ++j) l[j] = __shfl(logit, j * 4);

    float m = l[0];
    #pragma unroll
    for (int j = 1; j < 16; ++j) m = fmaxf(m, l[j]);
    float sum = 0.f, sc[16];
    #pragma unroll
    for (int j = 0; j < 16; ++j) { sc[j] = __expf(l[j] - m); sum += sc[j]; }
    float inv = 1.f / sum;
    #pragma unroll
    for (int j = 0; j < 16; ++j) sc[j] *= inv;

    float b0 = -1.f; int i0 = 0;
    #pragma unroll
    for (int j = 0; j < 16; ++j) if (sc[j] > b0) { b0 = sc[j]; i0 = j; }
    float b1 = -1.f; int i1 = 0;
    #pragma unroll
    for (int j = 0; j < 16; ++j) if (j != i0 && sc[j] > b1) { b1 = sc[j]; i1 = j; }
    float rs = 1.f / (b0 + b1);

    if (lane == 0) {
        topk_i[n * 2] = i0; topk_i[n * 2 + 1] = i1;
        topk_w[n * 2] = b0 * rs; topk_w[n * 2 + 1] = b1 * rs;
        atomicAdd(&c_blk[i0], 1); atomicAdd(&c_blk[i1], 1);
        #pragma unroll
        for (int j = 0; j < 16; ++j) atomicAdd(&p_blk[j], sc[j]);
    }
    __syncthreads();
    if (tid < 16) {
        atomicAdd(&p_sum[tid], p_blk[tid]);
        atomicAdd(&counts[tid], c_blk[tid]);
    }
}

__global__ __launch_bounds__(64) void offsets_kernel(const int* counts, int* offs) {
    if (threadIdx.x == 0) {
        int acc = 0;
        for (int e = 0; e < 16; ++e) { offs[e] = acc; acc += counts[e]; }
        offs[16] = acc;
    }
}

__global__ __launch_bounds__(256) void scatter_kernel(
    const int* __restrict__ topk_i, const float* __restrict__ topk_w,
    const int* __restrict__ offs, int* __restrict__ cursor,
    int* __restrict__ perm_t, float* __restrict__ perm_w) {
    int n = blockIdx.x * 256 + threadIdx.x;
    if (n >= NTOK) return;
    #pragma unroll
    for (int k = 0; k < 2; ++k) {
        int e = topk_i[n * 2 + k];
        int pos = atomicAdd(&cursor[e], 1);
        int s = offs[e] + pos;
        perm_t[s] = n;
        perm_w[s] = topk_w[n * 2 + k];
    }
}

// Fused SwiGLU FFN, MFMA bf16. blockIdx.y: 0..15 routed expert, 16 = shared expert.
// Out must be pre-zeroed; all paths atomicAdd.
// Wave grid 2(M) x 4(N): phase1 wave = 16 tokens x 96 i-rows (g AND u of same rows,
// so silu(g)*u is in-register); phase2 wave = 16 tokens x 192 d-cols.
__global__ __launch_bounds__(512, 1) void ffn_mfma_kernel(
    const float* __restrict__ x,
    const unsigned short* __restrict__ wsg, const unsigned short* __restrict__ wsu,
    const unsigned short* __restrict__ wsd,
    const unsigned short* __restrict__ wrg, const unsigned short* __restrict__ wru,
    const unsigned short* __restrict__ wrd,
    const int* __restrict__ perm_t, const float* __restrict__ perm_w,
    const int* __restrict__ offs, const int* __restrict__ counts,
    float* __restrict__ out) {
    __shared__ unsigned short xs[MT * XS_LD];   // 49,664 B
    __shared__ unsigned short hs[MT * HS_LD];   // 25,088 B
    __shared__ int   s_tok[MT];
    __shared__ float s_w[MT];

    int tid = threadIdx.x;
    int eY = blockIdx.y;
    int tile0 = blockIdx.x * MT;

    const unsigned short *gw, *uw, *dw;
    if (eY == 16) {
        gw = wsg; uw = wsu; dw = wsd;
        if (tid < MT) { s_tok[tid] = tile0 + tid; s_w[tid] = 1.f; }
    } else {
        int cnt = counts[eY];
        if (tile0 >= cnt) return;                 // uniform exit, before barriers
        size_t wo = (size_t)eY * (IDIM * DDIM);
        gw = wrg + wo; uw = wru + wo; dw = wrd + wo;
        int base = offs[eY];
        if (tid < MT) {
            int slot = tile0 + tid;
            if (slot < cnt) { s_tok[tid] = perm_t[base + slot]; s_w[tid] = perm_w[base + slot]; }
            else            { s_tok[tid] = 0;                   s_w[tid] = 0.f; }
        }
    }
    __syncthreads();

    // ---- stage x tile (fp32 -> bf16) into LDS ----
    {
        int row = tid >> 4;                 // 32 rows, 16 threads each
        int seg = (tid & 15) * 48;          // 48 floats per thread
        const float4* src = (const float4*)(x + (size_t)s_tok[row] * DDIM + seg);
        unsigned short* dst = xs + row * XS_LD + seg;
        #pragma unroll
        for (int i = 0; i < 12; ++i) {
            float4 v = src[i];
            ushort4 b;
            b.x = f2bf(v.x); b.y = f2bf(v.y); b.z = f2bf(v.z); b.w = f2bf(v.w);
            *(ushort4*)(dst + i * 4) = b;
        }
    }
    __syncthreads();

    int lane = tid & 63;
    int wave = tid >> 6;
    int wm = wave >> 2;              // 0..1 : token rows [wm*16, +16)
    int wn = wave & 3;               // 0..3
    int lr = lane & 15;              // frag row/col within 16
    int kg = (lane >> 4) * 8;        // k sub-offset within 32
    int jrow = (lane >> 4) * 4;      // C-frag row base

    // ---- phase 1: g,u = x @ {gw,uw}^T  (wave: 16 tokens x rows [wn*96, +96)) ----
    f32x4 accg[6], accu[6];
    #pragma unroll
    for (int f = 0; f < 6; ++f) { accg[f] = (f32x4)0.f; accu[f] = (f32x4)0.f; }

    const unsigned short* gpl = gw + (size_t)(wn * 96 + lr) * DDIM + kg;
    const unsigned short* upl = uw + (size_t)(wn * 96 + lr) * DDIM + kg;
    const unsigned short* apl = xs + (wm * 16 + lr) * XS_LD + kg;

    for (int ks = 0; ks < DDIM / 32; ++ks) {
        short8 a = *(const short8*)(apl + ks * 32);
        #pragma unroll
        for (int f = 0; f < 6; ++f) {
            short8 bg = *(const short8*)(gpl + (size_t)f * 16 * DDIM + ks * 32);
            short8 bu = *(const short8*)(upl + (size_t)f * 16 * DDIM + ks * 32);
            accg[f] = __builtin_amdgcn_mfma_f32_16x16x32_bf16(a, bg, accg[f], 0, 0, 0);
            accu[f] = __builtin_amdgcn_mfma_f32_16x16x32_bf16(a, bu, accu[f], 0, 0, 0);
        }
    }

    // silu(g)*u -> hs (C layout: col=lane&15 -> i-channel, row=(lane>>4)*4+j -> token)
    #pragma unroll
    for (int f = 0; f < 6; ++f) {
        #pragma unroll
        for (int j = 0; j < 4; ++j) {
            float g = accg[f][j], u = accu[f][j];
            float h = g / (1.f + __expf(-g)) * u;
            int tok = wm * 16 + jrow + j;
            int col = wn * 96 + f * 16 + lr;
            hs[tok * HS_LD + col] = f2bf(h);
        }
    }
    __syncthreads();

    // ---- phase 2: out_tile = h @ dw^T (wave: 16 tokens x d-cols [wn*192, +192)) ----
    f32x4 acc2[12];
    #pragma unroll
    for (int f = 0; f < 12; ++f) acc2[f] = (f32x4)0.f;

    const unsigned short* dpl = dw + (size_t)(wn * 192 + lr) * IDIM + kg;
    const unsigned short* hpl = hs + (wm * 16 + lr) * HS_LD + kg;

    for (int ks = 0; ks < IDIM / 32; ++ks) {
        short8 a = *(const short8*)(hpl + ks * 32);
        #pragma unroll
        for (int f = 0; f < 12; ++f) {
            short8 b = *(const short8*)(dpl + (size_t)f * 16 * IDIM + ks * 32);
            acc2[f] = __builtin_amdgcn_mfma_f32_16x16x32_bf16(a, b, acc2[f], 0, 0, 0);
        }
    }

    // ---- epilogue: scale by routing weight, accumulate into out ----
    #pragma unroll
    for (int j = 0; j < 4; ++j) {
        int tl = wm * 16 + jrow + j;
        int n = s_tok[tl];
        float w = s_w[tl];
        if (w == 0.f) continue;
        float* orow = out + (size_t)n * DDIM + wn * 192 + lr;
        #pragma unroll
        for (int f = 0; f < 12; ++f)
            atomicAdd(orow + f * 16, w * acc2[f][j]);
    }
}

__global__ __launch_bounds__(64) void aux_kernel(const int* counts, const float* p_sum,
                                                 float* out_aux) {
    if (threadIdx.x == 0) {
        float a = 0.f;
        for (int e = 0; e < 16; ++e) a += (float)counts[e] * p_sum[e];
        out_aux[0] = a * 16.f / ((float)NTOK * (float)NTOK);
    }
}

extern "C" void kernel_launch(void* const* d_in, const int* in_sizes, int n_in,
                              void* d_out, int out_size, void* d_ws, size_t ws_size,
                              hipStream_t stream) {
    const float* x      = (const float*)d_in[0];
    const float* gate_w = (const float*)d_in[1];
    const float* sg_w   = (const float*)d_in[2];
    const float* su_w   = (const float*)d_in[3];
    const float* sd_w   = (const float*)d_in[4];
    const float* rg_w   = (const float*)d_in[5];
    const float* ru_w   = (const float*)d_in[6];
    const float* rd_w   = (const float*)d_in[7];
    float* out = (float*)d_out;

    char* ws = (char*)d_ws;
    int*   counts = (int*)(ws + 0);
    int*   cursor = (int*)(ws + 64);
    int*   offs   = (int*)(ws + 128);
    float* p_sum  = (float*)(ws + 256);
    int*   topk_i = (int*)(ws + 512);
    float* topk_w = (float*)(ws + 16896);
    int*   perm_t = (int*)(ws + 33280);
    float* perm_w = (float*)(ws + 49664);
    unsigned short* wsg = (unsigned short*)(ws + WS_WSG);
    unsigned short* wsu = (unsigned short*)(ws + WS_WSU);
    unsigned short* wsd = (unsigned short*)(ws + WS_WSD);
    unsigned short* wrg = (unsigned short*)(ws + WS_WRG);
    unsigned short* wru = (unsigned short*)(ws + WS_WRU);
    unsigned short* wrd = (unsigned short*)(ws + WS_WRD);

    init_kernel<<<1, 64, 0, stream>>>(counts, cursor, offs, p_sum);
    hipMemsetAsync(d_out, 0, (size_t)out_size * 4, stream);

    // weight conversion fp32 -> bf16
    conv3_kernel<<<dim3(1024, 3), 256, 0, stream>>>(
        rg_w, ru_w, rd_w, wrg, wru, wrd, NEXP * IDIM * DDIM / 4);
    conv3_kernel<<<dim3(288, 3), 256, 0, stream>>>(
        sg_w, su_w, sd_w, wsg, wsu, wsd, IDIM * DDIM / 4);

    gate_kernel<<<NTOK / 4, 256, 0, stream>>>(x, gate_w, topk_i, topk_w, counts, p_sum);
    offsets_kernel<<<1, 64, 0, stream>>>(counts, offs);
    scatter_kernel<<<NTOK / 256, 256, 0, stream>>>(topk_i, topk_w, offs, cursor, perm_t, perm_w);

    // y = 0..15 routed experts, y = 16 shared expert (grid.x covers worst-case 2048 tokens)
    ffn_mfma_kernel<<<dim3(NTOK / MT, NEXP + 1), 512, 0, stream>>>(
        x, wsg, wsu, wsd, wrg, wru, wrd, perm_t, perm_w, offs, counts, out);

    aux_kernel<<<1, 64, 0, stream>>>(counts, p_sum, out + (size_t)NTOK * DDIM);
}

// Round 3
// 141.247 us; speedup vs baseline: 7.4480x; 2.6739x over previous
//
#include <hip/hip_runtime.h>
#include <math.h>

#define NTOK 2048
#define DDIM 768
#define IDIM 384
#define NEXP 16
#define XS_LD 776        // 768 + 8 pad (ushorts)
#define HS_LD 392        // 384 + 8 pad (ushorts)
#define NRT_MAX 144      // max routed m-tiles (4096/32 + 15 partials)
#define NSHT 64          // shared m-tiles (2048/32)

typedef __attribute__((ext_vector_type(8))) short short8;   // 8 bf16 = 4 VGPR
typedef __attribute__((ext_vector_type(4))) float f32x4;    // MFMA C/D

__device__ __forceinline__ unsigned short f2bf(float f) {
    unsigned int u = __float_as_uint(f);
    unsigned int r = (u + 0x7fffu + ((u >> 16) & 1u)) >> 16;   // RNE
    return (unsigned short)r;
}

// ---------------- workspace layout (bytes) ----------------
// 0    counts[16] | 64 cursor[16] | 128 offs[17] | 256 p_sum[16] | 320 n_rt
// 512  topk_i | 16896 topk_w | 33280 perm_t | 49664 perm_w
// 66048 tile_e[160] | 66688 tile_m[160]
#define WS_XB   1048576u                     // x bf16: 2048*768*2 = 3,145,728
#define WS_W1F  4194304u                     // w1 frag-major: 17*768*768*2 = 20,054,016
#define WS_WDF  24248320u                    // wd frag-major: 17*768*384*2 = 10,027,008
#define WS_H    34275328u                    // h: 6176*384*2 = 4,743,168 (end 39,018,496)

__global__ __launch_bounds__(64) void init_kernel(int* counts, int* cursor,
                                                  int* offs, float* p_sum) {
    int t = threadIdx.x;
    if (t < 16) { counts[t] = 0; cursor[t] = 0; p_sum[t] = 0.f; }
    if (t < 17) offs[t] = 0;
}

// x fp32 -> bf16 (plain layout). 768 blocks x 256 thr, 8 elems/thread.
__global__ __launch_bounds__(256) void conv_x_kernel(const float* __restrict__ x,
                                                     unsigned short* __restrict__ xb) {
    int i = blockIdx.x * 256 + threadIdx.x;          // 0..196607 chunks of 8
    const float* s = x + (size_t)i * 8;
    float4 v0 = *(const float4*)s, v1 = *(const float4*)(s + 4);
    short8 o;
    o[0]=f2bf(v0.x); o[1]=f2bf(v0.y); o[2]=f2bf(v0.z); o[3]=f2bf(v0.w);
    o[4]=f2bf(v1.x); o[5]=f2bf(v1.y); o[6]=f2bf(v1.z); o[7]=f2bf(v1.w);
    *(short8*)(xb + (size_t)i * 8) = o;
}

// W1 (g,u interleaved 16g+16u groups) -> fragment-major bf16:
// w1f[e][rg(48)][ks(24)][lane(64)][8]; lane: row=b16*16+(l&15), k=ks*32+(l>>4)*8
// grid (288, 17)
__global__ __launch_bounds__(256) void conv_w1f_kernel(
    const float* __restrict__ rgw, const float* __restrict__ ruw,
    const float* __restrict__ sgw, const float* __restrict__ suw,
    unsigned short* __restrict__ w1f) {
    int E = blockIdx.y;
    const float* gsrc = (E == 16) ? sgw : rgw + (size_t)E * (IDIM * DDIM);
    const float* usrc = (E == 16) ? suw : ruw + (size_t)E * (IDIM * DDIM);
    int i = blockIdx.x * 256 + threadIdx.x;          // 0..73727
    int lane = i & 63;
    int fi = i >> 6;                                 // 0..1151
    int ks = fi % 24, rg = fi / 24;                  // rg 0..47
    int b16 = rg >> 1, gu = rg & 1;
    const float* s = (gu ? usrc : gsrc)
                   + (size_t)(b16 * 16 + (lane & 15)) * DDIM + ks * 32 + (lane >> 4) * 8;
    float4 v0 = *(const float4*)s, v1 = *(const float4*)(s + 4);
    short8 o;
    o[0]=f2bf(v0.x); o[1]=f2bf(v0.y); o[2]=f2bf(v0.z); o[3]=f2bf(v0.w);
    o[4]=f2bf(v1.x); o[5]=f2bf(v1.y); o[6]=f2bf(v1.z); o[7]=f2bf(v1.w);
    *(short8*)(w1f + (size_t)E * (DDIM * DDIM) + (size_t)i * 8) = o;
}

// wd -> fragment-major: wdf[e][cg(48)][ks(12)][lane(64)][8];
// lane: dcol=cg*16+(l&15), k=ks*32+(l>>4)*8.  grid (144, 17)
__global__ __launch_bounds__(256) void conv_wdf_kernel(
    const float* __restrict__ rdw, const float* __restrict__ sdw,
    unsigned short* __restrict__ wdf) {
    int E = blockIdx.y;
    const float* src = (E == 16) ? sdw : rdw + (size_t)E * (DDIM * IDIM);
    int i = blockIdx.x * 256 + threadIdx.x;          // 0..36863
    int lane = i & 63;
    int fi = i >> 6;                                 // 0..575
    int ks = fi % 12, cg = fi / 12;                  // cg 0..47
    const float* s = src + (size_t)(cg * 16 + (lane & 15)) * IDIM + ks * 32 + (lane >> 4) * 8;
    float4 v0 = *(const float4*)s, v1 = *(const float4*)(s + 4);
    short8 o;
    o[0]=f2bf(v0.x); o[1]=f2bf(v0.y); o[2]=f2bf(v0.z); o[3]=f2bf(v0.w);
    o[4]=f2bf(v1.x); o[5]=f2bf(v1.y); o[6]=f2bf(v1.z); o[7]=f2bf(v1.w);
    *(short8*)(wdf + (size_t)E * (DDIM * IDIM) + (size_t)i * 8) = o;
}

__global__ __launch_bounds__(256) void gate_kernel(
    const float* __restrict__ x, const float* __restrict__ gate_w,
    int* __restrict__ topk_i, float* __restrict__ topk_w,
    int* __restrict__ counts, float* __restrict__ p_sum) {
    __shared__ float p_blk[16];
    __shared__ int   c_blk[16];
    int tid = threadIdx.x;
    if (tid < 16) { p_blk[tid] = 0.f; c_blk[tid] = 0; }
    __syncthreads();

    int wave = tid >> 6, lane = tid & 63;
    int n = blockIdx.x * 4 + wave;
    int e = lane >> 2, q = lane & 3;
    const float4* xr = (const float4*)(x + (size_t)n * DDIM);
    const float4* wr = (const float4*)(gate_w + (size_t)e * DDIM);
    float s = 0.f;
    #pragma unroll 4
    for (int k = q * 48; k < q * 48 + 48; ++k) {
        float4 a = xr[k], b = wr[k];
        s += a.x * b.x + a.y * b.y + a.z * b.z + a.w * b.w;
    }
    s += __shfl_xor(s, 1);
    s += __shfl_xor(s, 2);
    float logit = s * 2.5f;

    float l[16];
    #pragma unroll
    for (int j = 0; j < 16; ++j) l[j] = __shfl(logit, j * 4);

    float m = l[0];
    #pragma unroll
    for (int j = 1; j < 16; ++j) m = fmaxf(m, l[j]);
    float sum = 0.f, sc[16];
    #pragma unroll
    for (int j = 0; j < 16; ++j) { sc[j] = __expf(l[j] - m); sum += sc[j]; }
    float inv = 1.f / sum;
    #pragma unroll
    for (int j = 0; j < 16; ++j) sc[j] *= inv;

    float b0 = -1.f; int i0 = 0;
    #pragma unroll
    for (int j = 0; j < 16; ++j) if (sc[j] > b0) { b0 = sc[j]; i0 = j; }
    float b1 = -1.f; int i1 = 0;
    #pragma unroll
    for (int j = 0; j < 16; ++j) if (j != i0 && sc[j] > b1) { b1 = sc[j]; i1 = j; }
    float rs = 1.f / (b0 + b1);

    if (lane == 0) {
        topk_i[n * 2] = i0; topk_i[n * 2 + 1] = i1;
        topk_w[n * 2] = b0 * rs; topk_w[n * 2 + 1] = b1 * rs;
        atomicAdd(&c_blk[i0], 1); atomicAdd(&c_blk[i1], 1);
        #pragma unroll
        for (int j = 0; j < 16; ++j) atomicAdd(&p_blk[j], sc[j]);
    }
    __syncthreads();
    if (tid < 16) {
        atomicAdd(&p_sum[tid], p_blk[tid]);
        atomicAdd(&counts[tid], c_blk[tid]);
    }
}

// prefix sums + (expert, m-tile) worklist
__global__ __launch_bounds__(64) void offsets_kernel(const int* counts, int* offs,
                                                     int* tile_e, int* tile_m, int* n_rt) {
    if (threadIdx.x == 0) {
        int acc = 0, n = 0;
        for (int e = 0; e < 16; ++e) {
            offs[e] = acc;
            int c = counts[e];
            for (int t = 0; t < c; t += 32) { tile_e[n] = e; tile_m[n] = acc + t; ++n; }
            acc += c;
        }
        offs[16] = acc;
        *n_rt = n;
    }
}

__global__ __launch_bounds__(256) void scatter_kernel(
    const int* __restrict__ topk_i, const float* __restrict__ topk_w,
    const int* __restrict__ offs, int* __restrict__ cursor,
    int* __restrict__ perm_t, float* __restrict__ perm_w) {
    int n = blockIdx.x * 256 + threadIdx.x;
    if (n >= NTOK) return;
    #pragma unroll
    for (int k = 0; k < 2; ++k) {
        int e = topk_i[n * 2 + k];
        int pos = atomicAdd(&cursor[e], 1);
        int s = offs[e] + pos;
        perm_t[s] = n;
        perm_w[s] = topk_w[n * 2 + k];
    }
}

// phase 1: g,u GEMM + fused SiLU -> h.  grid (NSHT + NRT_MAX, 6), 256 thr.
// block: 32 tokens x 64 i-channels (128 interleaved W1 rows); wave = i-block y*4+wave.
__global__ __launch_bounds__(256, 3) void p1_kernel(
    const unsigned short* __restrict__ xb, const unsigned short* __restrict__ w1f,
    const int* __restrict__ perm_t,
    const int* __restrict__ offs, const int* __restrict__ counts,
    const int* __restrict__ tile_e, const int* __restrict__ tile_m,
    const int* __restrict__ n_rt,
    unsigned short* __restrict__ h) {
    __shared__ unsigned short xs[32 * XS_LD];   // 49,664 B
    __shared__ int s_tok[32];
    __shared__ int s_hrow[32];

    int tid = threadIdx.x;
    int bx = blockIdx.x, y = blockIdx.y;
    int e;
    if (bx < NSHT) {
        e = 16;
        if (tid < 32) { int t = bx * 32 + tid; s_tok[tid] = t; s_hrow[tid] = 4096 + t; }
    } else {
        int r = bx - NSHT;
        if (r >= *n_rt) return;
        e = tile_e[r];
        int m0 = tile_m[r];
        int end = offs[e] + counts[e];
        if (tid < 32) {
            int slot = m0 + tid;
            bool v = slot < end;
            s_tok[tid]  = v ? perm_t[slot] : 0;
            s_hrow[tid] = v ? slot : 6144 + tid;   // dummy rows, never read
        }
    }
    __syncthreads();

    for (int c = tid; c < 32 * 96; c += 256) {
        int row = c / 96, off = (c - row * 96) * 8;
        *(short8*)(xs + row * XS_LD + off) =
            *(const short8*)(xb + (size_t)s_tok[row] * DDIM + off);
    }
    __syncthreads();

    int lane = tid & 63, wave = tid >> 6;
    int lr = lane & 15, kg = (lane >> 4) * 8, jrow = (lane >> 4) * 4;

    const unsigned short* pg = w1f + ((((size_t)e * 48 + (y * 8 + wave * 2    )) * 24) * 64 + lane) * 8;
    const unsigned short* pu = w1f + ((((size_t)e * 48 + (y * 8 + wave * 2 + 1)) * 24) * 64 + lane) * 8;

    f32x4 accg0 = (f32x4)0.f, accg1 = (f32x4)0.f, accu0 = (f32x4)0.f, accu1 = (f32x4)0.f;
    for (int ks = 0; ks < 24; ++ks) {
        short8 a0 = *(const short8*)(xs + lr * XS_LD + ks * 32 + kg);
        short8 a1 = *(const short8*)(xs + (16 + lr) * XS_LD + ks * 32 + kg);
        short8 bg = *(const short8*)(pg + (size_t)ks * 512);
        short8 bu = *(const short8*)(pu + (size_t)ks * 512);
        accg0 = __builtin_amdgcn_mfma_f32_16x16x32_bf16(a0, bg, accg0, 0, 0, 0);
        accg1 = __builtin_amdgcn_mfma_f32_16x16x32_bf16(a1, bg, accg1, 0, 0, 0);
        accu0 = __builtin_amdgcn_mfma_f32_16x16x32_bf16(a0, bu, accu0, 0, 0, 0);
        accu1 = __builtin_amdgcn_mfma_f32_16x16x32_bf16(a1, bu, accu1, 0, 0, 0);
    }

    int colg = y * 64 + wave * 16 + lr;
    #pragma unroll
    for (int m = 0; m < 2; ++m) {
        #pragma unroll
        for (int j = 0; j < 4; ++j) {
            int tl = m * 16 + jrow + j;
            float g = m ? accg1[j] : accg0[j];
            float u = m ? accu1[j] : accu0[j];
            float hv = g / (1.f + __expf(-g)) * u;
            h[(size_t)s_hrow[tl] * IDIM + colg] = f2bf(hv);
        }
    }
}

// phase 2: out GEMM + weighted atomic accumulate. grid (NSHT + NRT_MAX, 6), 256 thr.
// block: 32 slots x 128 d-cols; wave: 32 tok x 32 d-cols (2 col-frags).
__global__ __launch_bounds__(256, 4) void p2_kernel(
    const unsigned short* __restrict__ h, const unsigned short* __restrict__ wdf,
    const int* __restrict__ perm_t, const float* __restrict__ perm_w,
    const int* __restrict__ offs, const int* __restrict__ counts,
    const int* __restrict__ tile_e, const int* __restrict__ tile_m,
    const int* __restrict__ n_rt,
    float* __restrict__ out) {
    __shared__ unsigned short hs[32 * HS_LD];   // 25,088 B
    __shared__ int   s_tok[32];
    __shared__ float s_w[32];
    __shared__ int   s_arow[32];

    int tid = threadIdx.x;
    int bx = blockIdx.x, y = blockIdx.y;
    int e;
    if (bx < NSHT) {
        e = 16;
        if (tid < 32) {
            int t = bx * 32 + tid;
            s_tok[tid] = t; s_w[tid] = 1.f; s_arow[tid] = 4096 + t;
        }
    } else {
        int r = bx - NSHT;
        if (r >= *n_rt) return;
        e = tile_e[r];
        int m0 = tile_m[r];
        int end = offs[e] + counts[e];
        if (tid < 32) {
            int slot = m0 + tid;
            bool v = slot < end;
            s_tok[tid]  = v ? perm_t[slot] : 0;
            s_w[tid]    = v ? perm_w[slot] : 0.f;
            s_arow[tid] = v ? slot : offs[e];      // clamp: always-valid finite row
        }
    }
    __syncthreads();

    for (int c = tid; c < 32 * 48; c += 256) {
        int row = c / 48, off = (c - row * 48) * 8;
        *(short8*)(hs + row * HS_LD + off) =
            *(const short8*)(h + (size_t)s_arow[row] * IDIM + off);
    }
    __syncthreads();

    int lane = tid & 63, wave = tid >> 6;
    int lr = lane & 15, kg = (lane >> 4) * 8, jrow = (lane >> 4) * 4;

    const unsigned short* p0 = wdf + ((((size_t)e * 48 + (y * 8 + wave * 2    )) * 12) * 64 + lane) * 8;
    const unsigned short* p1 = wdf + ((((size_t)e * 48 + (y * 8 + wave * 2 + 1)) * 12) * 64 + lane) * 8;

    f32x4 acc00 = (f32x4)0.f, acc01 = (f32x4)0.f, acc10 = (f32x4)0.f, acc11 = (f32x4)0.f;
    for (int ks = 0; ks < 12; ++ks) {
        short8 a0 = *(const short8*)(hs + lr * HS_LD + ks * 32 + kg);
        short8 a1 = *(const short8*)(hs + (16 + lr) * HS_LD + ks * 32 + kg);
        short8 b0 = *(const short8*)(p0 + (size_t)ks * 512);
        short8 b1 = *(const short8*)(p1 + (size_t)ks * 512);
        acc00 = __builtin_amdgcn_mfma_f32_16x16x32_bf16(a0, b0, acc00, 0, 0, 0);
        acc01 = __builtin_amdgcn_mfma_f32_16x16x32_bf16(a1, b0, acc01, 0, 0, 0);
        acc10 = __builtin_amdgcn_mfma_f32_16x16x32_bf16(a0, b1, acc10, 0, 0, 0);
        acc11 = __builtin_amdgcn_mfma_f32_16x16x32_bf16(a1, b1, acc11, 0, 0, 0);
    }

    int col0 = y * 128 + wave * 32 + lr;
    #pragma unroll
    for (int m = 0; m < 2; ++m) {
        #pragma unroll
        for (int j = 0; j < 4; ++j) {
            int tl = m * 16 + jrow + j;
            float w = s_w[tl];
            if (w == 0.f) continue;
            float* orow = out + (size_t)s_tok[tl] * DDIM;
            float v0 = m ? acc01[j] : acc00[j];
            float v1 = m ? acc11[j] : acc10[j];
            atomicAdd(orow + col0,      w * v0);
            atomicAdd(orow + col0 + 16, w * v1);
        }
    }
}

__global__ __launch_bounds__(64) void aux_kernel(const int* counts, const float* p_sum,
                                                 float* out_aux) {
    if (threadIdx.x == 0) {
        float a = 0.f;
        for (int e = 0; e < 16; ++e) a += (float)counts[e] * p_sum[e];
        out_aux[0] = a * 16.f / ((float)NTOK * (float)NTOK);
    }
}

extern "C" void kernel_launch(void* const* d_in, const int* in_sizes, int n_in,
                              void* d_out, int out_size, void* d_ws, size_t ws_size,
                              hipStream_t stream) {
    const float* x      = (const float*)d_in[0];
    const float* gate_w = (const float*)d_in[1];
    const float* sg_w   = (const float*)d_in[2];
    const float* su_w   = (const float*)d_in[3];
    const float* sd_w   = (const float*)d_in[4];
    const float* rg_w   = (const float*)d_in[5];
    const float* ru_w   = (const float*)d_in[6];
    const float* rd_w   = (const float*)d_in[7];
    float* out = (float*)d_out;

    char* ws = (char*)d_ws;
    int*   counts = (int*)(ws + 0);
    int*   cursor = (int*)(ws + 64);
    int*   offs   = (int*)(ws + 128);
    float* p_sum  = (float*)(ws + 256);
    int*   n_rt   = (int*)(ws + 320);
    int*   topk_i = (int*)(ws + 512);
    float* topk_w = (float*)(ws + 16896);
    int*   perm_t = (int*)(ws + 33280);
    float* perm_w = (float*)(ws + 49664);
    int*   tile_e = (int*)(ws + 66048);
    int*   tile_m = (int*)(ws + 66688);
    unsigned short* xb  = (unsigned short*)(ws + WS_XB);
    unsigned short* w1f = (unsigned short*)(ws + WS_W1F);
    unsigned short* wdf = (unsigned short*)(ws + WS_WDF);
    unsigned short* hbuf= (unsigned short*)(ws + WS_H);

    init_kernel<<<1, 64, 0, stream>>>(counts, cursor, offs, p_sum);
    hipMemsetAsync(d_out, 0, (size_t)out_size * 4, stream);

    conv_x_kernel<<<768, 256, 0, stream>>>(x, xb);
    conv_w1f_kernel<<<dim3(288, 17), 256, 0, stream>>>(rg_w, ru_w, sg_w, su_w, w1f);
    conv_wdf_kernel<<<dim3(144, 17), 256, 0, stream>>>(rd_w, sd_w, wdf);

    gate_kernel<<<NTOK / 4, 256, 0, stream>>>(x, gate_w, topk_i, topk_w, counts, p_sum);
    offsets_kernel<<<1, 64, 0, stream>>>(counts, offs, tile_e, tile_m, n_rt);
    scatter_kernel<<<NTOK / 256, 256, 0, stream>>>(topk_i, topk_w, offs, cursor, perm_t, perm_w);

    p1_kernel<<<dim3(NSHT + NRT_MAX, 6), 256, 0, stream>>>(
        xb, w1f, perm_t, offs, counts, tile_e, tile_m, n_rt, hbuf);
    p2_kernel<<<dim3(NSHT + NRT_MAX, 6), 256, 0, stream>>>(
        hbuf, wdf, perm_t, perm_w, offs, counts, tile_e, tile_m, n_rt, out);

    aux_kernel<<<1, 64, 0, stream>>>(counts, p_sum, out + (size_t)NTOK * DDIM);
}

// Round 4
// 137.837 us; speedup vs baseline: 7.6322x; 1.0247x over previous
//
#include <hip/hip_runtime.h>
#include <math.h>

#define NTOK 2048
#define DDIM 768
#define IDIM 384
#define NEXP 16
#define XS_LD 776        // 768 + 8 pad (ushorts)
#define HS_LD 392        // 384 + 8 pad (ushorts)
#define NRT_MAX 144      // max routed m-tiles (4096/32 + 15 partials)
#define NSHT 64          // shared m-tiles (2048/32)

typedef __attribute__((ext_vector_type(8))) short short8;   // 8 bf16 = 4 VGPR
typedef __attribute__((ext_vector_type(4))) float f32x4;    // MFMA C/D

__device__ __forceinline__ unsigned short f2bf(float f) {
    unsigned int u = __float_as_uint(f);
    unsigned int r = (u + 0x7fffu + ((u >> 16) & 1u)) >> 16;   // RNE
    return (unsigned short)r;
}

// ---------------- workspace layout (bytes) ----------------
// 0    counts[16] | 64 cursor[16] | 128 offs[17] | 256 p_sum[16] | 320 n_rt
// 512  topk_i | 16896 topk_w | 33280 perm_t | 49664 perm_w
// 66048 tile_e[160] | 66688 tile_m[160]
#define WS_XB   1048576u                     // x bf16: 2048*768*2 = 3,145,728
#define WS_W1F  4194304u                     // w1 frag-major: 17*768*768*2 = 20,054,016
#define WS_WDF  24248320u                    // wd frag-major: 17*768*384*2 = 10,027,008
#define WS_H    34275328u                    // h: 6176*384*2 = 4,743,168 (end 39,018,496)

// zero d_out (float4-vectorized) + init control scalars (block 0).
// grid must be >= out4 count / 256.
__global__ __launch_bounds__(256) void zero_init_kernel(
    float4* __restrict__ out4, int n4,
    int* counts, int* cursor, int* offs, float* p_sum) {
    int i = blockIdx.x * 256 + threadIdx.x;
    if (i < n4) out4[i] = make_float4(0.f, 0.f, 0.f, 0.f);
    if (blockIdx.x == 0) {
        int t = threadIdx.x;
        if (t < 16) { counts[t] = 0; cursor[t] = 0; p_sum[t] = 0.f; }
        if (t < 17) offs[t] = 0;
    }
}

// x fp32 -> bf16 (plain layout). 768 blocks x 256 thr, 8 elems/thread.
__global__ __launch_bounds__(256) void conv_x_kernel(const float* __restrict__ x,
                                                     unsigned short* __restrict__ xb) {
    int i = blockIdx.x * 256 + threadIdx.x;          // 0..196607 chunks of 8
    const float* s = x + (size_t)i * 8;
    float4 v0 = *(const float4*)s, v1 = *(const float4*)(s + 4);
    short8 o;
    o[0]=f2bf(v0.x); o[1]=f2bf(v0.y); o[2]=f2bf(v0.z); o[3]=f2bf(v0.w);
    o[4]=f2bf(v1.x); o[5]=f2bf(v1.y); o[6]=f2bf(v1.z); o[7]=f2bf(v1.w);
    *(short8*)(xb + (size_t)i * 8) = o;
}

// W1 (g,u interleaved 16g+16u groups) -> fragment-major bf16:
// w1f[e][rg(48)][ks(24)][lane(64)][8]; lane: row=b16*16+(l&15), k=ks*32+(l>>4)*8
// grid (288, 17)
__global__ __launch_bounds__(256) void conv_w1f_kernel(
    const float* __restrict__ rgw, const float* __restrict__ ruw,
    const float* __restrict__ sgw, const float* __restrict__ suw,
    unsigned short* __restrict__ w1f) {
    int E = blockIdx.y;
    const float* gsrc = (E == 16) ? sgw : rgw + (size_t)E * (IDIM * DDIM);
    const float* usrc = (E == 16) ? suw : ruw + (size_t)E * (IDIM * DDIM);
    int i = blockIdx.x * 256 + threadIdx.x;          // 0..73727
    int lane = i & 63;
    int fi = i >> 6;                                 // 0..1151
    int ks = fi % 24, rg = fi / 24;                  // rg 0..47
    int b16 = rg >> 1, gu = rg & 1;
    const float* s = (gu ? usrc : gsrc)
                   + (size_t)(b16 * 16 + (lane & 15)) * DDIM + ks * 32 + (lane >> 4) * 8;
    float4 v0 = *(const float4*)s, v1 = *(const float4*)(s + 4);
    short8 o;
    o[0]=f2bf(v0.x); o[1]=f2bf(v0.y); o[2]=f2bf(v0.z); o[3]=f2bf(v0.w);
    o[4]=f2bf(v1.x); o[5]=f2bf(v1.y); o[6]=f2bf(v1.z); o[7]=f2bf(v1.w);
    *(short8*)(w1f + (size_t)E * (DDIM * DDIM) + (size_t)i * 8) = o;
}

// wd -> fragment-major: wdf[e][cg(48)][ks(12)][lane(64)][8];
// lane: dcol=cg*16+(l&15), k=ks*32+(l>>4)*8.  grid (144, 17)
__global__ __launch_bounds__(256) void conv_wdf_kernel(
    const float* __restrict__ rdw, const float* __restrict__ sdw,
    unsigned short* __restrict__ wdf) {
    int E = blockIdx.y;
    const float* src = (E == 16) ? sdw : rdw + (size_t)E * (DDIM * IDIM);
    int i = blockIdx.x * 256 + threadIdx.x;          // 0..36863
    int lane = i & 63;
    int fi = i >> 6;                                 // 0..575
    int ks = fi % 12, cg = fi / 12;                  // cg 0..47
    const float* s = src + (size_t)(cg * 16 + (lane & 15)) * IDIM + ks * 32 + (lane >> 4) * 8;
    float4 v0 = *(const float4*)s, v1 = *(const float4*)(s + 4);
    short8 o;
    o[0]=f2bf(v0.x); o[1]=f2bf(v0.y); o[2]=f2bf(v0.z); o[3]=f2bf(v0.w);
    o[4]=f2bf(v1.x); o[5]=f2bf(v1.y); o[6]=f2bf(v1.z); o[7]=f2bf(v1.w);
    *(short8*)(wdf + (size_t)E * (DDIM * IDIM) + (size_t)i * 8) = o;
}

__global__ __launch_bounds__(256) void gate_kernel(
    const float* __restrict__ x, const float* __restrict__ gate_w,
    int* __restrict__ topk_i, float* __restrict__ topk_w,
    int* __restrict__ counts, float* __restrict__ p_sum) {
    __shared__ float p_blk[16];
    __shared__ int   c_blk[16];
    int tid = threadIdx.x;
    if (tid < 16) { p_blk[tid] = 0.f; c_blk[tid] = 0; }
    __syncthreads();

    int wave = tid >> 6, lane = tid & 63;
    int n = blockIdx.x * 4 + wave;
    int e = lane >> 2, q = lane & 3;
    const float4* xr = (const float4*)(x + (size_t)n * DDIM);
    const float4* wr = (const float4*)(gate_w + (size_t)e * DDIM);
    float s = 0.f;
    #pragma unroll 4
    for (int k = q * 48; k < q * 48 + 48; ++k) {
        float4 a = xr[k], b = wr[k];
        s += a.x * b.x + a.y * b.y + a.z * b.z + a.w * b.w;
    }
    s += __shfl_xor(s, 1);
    s += __shfl_xor(s, 2);
    float logit = s * 2.5f;

    float l[16];
    #pragma unroll
    for (int j = 0; j < 16; ++j) l[j] = __shfl(logit, j * 4);

    float m = l[0];
    #pragma unroll
    for (int j = 1; j < 16; ++j) m = fmaxf(m, l[j]);
    float sum = 0.f, sc[16];
    #pragma unroll
    for (int j = 0; j < 16; ++j) { sc[j] = __expf(l[j] - m); sum += sc[j]; }
    float inv = 1.f / sum;
    #pragma unroll
    for (int j = 0; j < 16; ++j) sc[j] *= inv;

    float b0 = -1.f; int i0 = 0;
    #pragma unroll
    for (int j = 0; j < 16; ++j) if (sc[j] > b0) { b0 = sc[j]; i0 = j; }
    float b1 = -1.f; int i1 = 0;
    #pragma unroll
    for (int j = 0; j < 16; ++j) if (j != i0 && sc[j] > b1) { b1 = sc[j]; i1 = j; }
    float rs = 1.f / (b0 + b1);

    if (lane == 0) {
        topk_i[n * 2] = i0; topk_i[n * 2 + 1] = i1;
        topk_w[n * 2] = b0 * rs; topk_w[n * 2 + 1] = b1 * rs;
        atomicAdd(&c_blk[i0], 1); atomicAdd(&c_blk[i1], 1);
        #pragma unroll
        for (int j = 0; j < 16; ++j) atomicAdd(&p_blk[j], sc[j]);
    }
    __syncthreads();
    if (tid < 16) {
        atomicAdd(&p_sum[tid], p_blk[tid]);
        atomicAdd(&counts[tid], c_blk[tid]);
    }
}

// prefix sums + (expert, m-tile) worklist
__global__ __launch_bounds__(64) void offsets_kernel(const int* counts, int* offs,
                                                     int* tile_e, int* tile_m, int* n_rt) {
    if (threadIdx.x == 0) {
        int acc = 0, n = 0;
        for (int e = 0; e < 16; ++e) {
            offs[e] = acc;
            int c = counts[e];
            for (int t = 0; t < c; t += 32) { tile_e[n] = e; tile_m[n] = acc + t; ++n; }
            acc += c;
        }
        offs[16] = acc;
        *n_rt = n;
    }
}

__global__ __launch_bounds__(256) void scatter_kernel(
    const int* __restrict__ topk_i, const float* __restrict__ topk_w,
    const int* __restrict__ offs, int* __restrict__ cursor,
    int* __restrict__ perm_t, float* __restrict__ perm_w) {
    int n = blockIdx.x * 256 + threadIdx.x;
    if (n >= NTOK) return;
    #pragma unroll
    for (int k = 0; k < 2; ++k) {
        int e = topk_i[n * 2 + k];
        int pos = atomicAdd(&cursor[e], 1);
        int s = offs[e] + pos;
        perm_t[s] = n;
        perm_w[s] = topk_w[n * 2 + k];
    }
}

// phase 1: g,u GEMM + fused SiLU -> h.  grid (NSHT + NRT_MAX, 6), 256 thr.
// block: 32 tokens x 64 i-channels (128 interleaved W1 rows); wave = i-block y*4+wave.
__global__ __launch_bounds__(256, 3) void p1_kernel(
    const unsigned short* __restrict__ xb, const unsigned short* __restrict__ w1f,
    const int* __restrict__ perm_t,
    const int* __restrict__ offs, const int* __restrict__ counts,
    const int* __restrict__ tile_e, const int* __restrict__ tile_m,
    const int* __restrict__ n_rt,
    unsigned short* __restrict__ h) {
    __shared__ unsigned short xs[32 * XS_LD];   // 49,664 B
    __shared__ int s_tok[32];
    __shared__ int s_hrow[32];

    int tid = threadIdx.x;
    int bx = blockIdx.x, y = blockIdx.y;
    int e;
    if (bx < NSHT) {
        e = 16;
        if (tid < 32) { int t = bx * 32 + tid; s_tok[tid] = t; s_hrow[tid] = 4096 + t; }
    } else {
        int r = bx - NSHT;
        if (r >= *n_rt) return;
        e = tile_e[r];
        int m0 = tile_m[r];
        int end = offs[e] + counts[e];
        if (tid < 32) {
            int slot = m0 + tid;
            bool v = slot < end;
            s_tok[tid]  = v ? perm_t[slot] : 0;
            s_hrow[tid] = v ? slot : 6144 + tid;   // dummy rows, never read
        }
    }
    __syncthreads();

    for (int c = tid; c < 32 * 96; c += 256) {
        int row = c / 96, off = (c - row * 96) * 8;
        *(short8*)(xs + row * XS_LD + off) =
            *(const short8*)(xb + (size_t)s_tok[row] * DDIM + off);
    }
    __syncthreads();

    int lane = tid & 63, wave = tid >> 6;
    int lr = lane & 15, kg = (lane >> 4) * 8, jrow = (lane >> 4) * 4;

    const unsigned short* pg = w1f + ((((size_t)e * 48 + (y * 8 + wave * 2    )) * 24) * 64 + lane) * 8;
    const unsigned short* pu = w1f + ((((size_t)e * 48 + (y * 8 + wave * 2 + 1)) * 24) * 64 + lane) * 8;

    f32x4 accg0 = (f32x4)0.f, accg1 = (f32x4)0.f, accu0 = (f32x4)0.f, accu1 = (f32x4)0.f;
    for (int ks = 0; ks < 24; ++ks) {
        short8 a0 = *(const short8*)(xs + lr * XS_LD + ks * 32 + kg);
        short8 a1 = *(const short8*)(xs + (16 + lr) * XS_LD + ks * 32 + kg);
        short8 bg = *(const short8*)(pg + (size_t)ks * 512);
        short8 bu = *(const short8*)(pu + (size_t)ks * 512);
        accg0 = __builtin_amdgcn_mfma_f32_16x16x32_bf16(a0, bg, accg0, 0, 0, 0);
        accg1 = __builtin_amdgcn_mfma_f32_16x16x32_bf16(a1, bg, accg1, 0, 0, 0);
        accu0 = __builtin_amdgcn_mfma_f32_16x16x32_bf16(a0, bu, accu0, 0, 0, 0);
        accu1 = __builtin_amdgcn_mfma_f32_16x16x32_bf16(a1, bu, accu1, 0, 0, 0);
    }

    int colg = y * 64 + wave * 16 + lr;
    #pragma unroll
    for (int m = 0; m < 2; ++m) {
        #pragma unroll
        for (int j = 0; j < 4; ++j) {
            int tl = m * 16 + jrow + j;
            float g = m ? accg1[j] : accg0[j];
            float u = m ? accu1[j] : accu0[j];
            float hv = g / (1.f + __expf(-g)) * u;
            h[(size_t)s_hrow[tl] * IDIM + colg] = f2bf(hv);
        }
    }
}

// phase 2: out GEMM + weighted atomic accumulate. grid (NSHT + NRT_MAX, 6), 256 thr.
// block: 32 slots x 128 d-cols; wave: 32 tok x 32 d-cols (2 col-frags).
__global__ __launch_bounds__(256, 4) void p2_kernel(
    const unsigned short* __restrict__ h, const unsigned short* __restrict__ wdf,
    const int* __restrict__ perm_t, const float* __restrict__ perm_w,
    const int* __restrict__ offs, const int* __restrict__ counts,
    const int* __restrict__ tile_e, const int* __restrict__ tile_m,
    const int* __restrict__ n_rt,
    float* __restrict__ out) {
    __shared__ unsigned short hs[32 * HS_LD];   // 25,088 B
    __shared__ int   s_tok[32];
    __shared__ float s_w[32];
    __shared__ int   s_arow[32];

    int tid = threadIdx.x;
    int bx = blockIdx.x, y = blockIdx.y;
    int e;
    if (bx < NSHT) {
        e = 16;
        if (tid < 32) {
            int t = bx * 32 + tid;
            s_tok[tid] = t; s_w[tid] = 1.f; s_arow[tid] = 4096 + t;
        }
    } else {
        int r = bx - NSHT;
        if (r >= *n_rt) return;
        e = tile_e[r];
        int m0 = tile_m[r];
        int end = offs[e] + counts[e];
        if (tid < 32) {
            int slot = m0 + tid;
            bool v = slot < end;
            s_tok[tid]  = v ? perm_t[slot] : 0;
            s_w[tid]    = v ? perm_w[slot] : 0.f;
            s_arow[tid] = v ? slot : offs[e];      // clamp: always-valid finite row
        }
    }
    __syncthreads();

    for (int c = tid; c < 32 * 48; c += 256) {
        int row = c / 48, off = (c - row * 48) * 8;
        *(short8*)(hs + row * HS_LD + off) =
            *(const short8*)(h + (size_t)s_arow[row] * IDIM + off);
    }
    __syncthreads();

    int lane = tid & 63, wave = tid >> 6;
    int lr = lane & 15, kg = (lane >> 4) * 8, jrow = (lane >> 4) * 4;

    const unsigned short* p0 = wdf + ((((size_t)e * 48 + (y * 8 + wave * 2    )) * 12) * 64 + lane) * 8;
    const unsigned short* p1 = wdf + ((((size_t)e * 48 + (y * 8 + wave * 2 + 1)) * 12) * 64 + lane) * 8;

    f32x4 acc00 = (f32x4)0.f, acc01 = (f32x4)0.f, acc10 = (f32x4)0.f, acc11 = (f32x4)0.f;
    for (int ks = 0; ks < 12; ++ks) {
        short8 a0 = *(const short8*)(hs + lr * HS_LD + ks * 32 + kg);
        short8 a1 = *(const short8*)(hs + (16 + lr) * HS_LD + ks * 32 + kg);
        short8 b0 = *(const short8*)(p0 + (size_t)ks * 512);
        short8 b1 = *(const short8*)(p1 + (size_t)ks * 512);
        acc00 = __builtin_amdgcn_mfma_f32_16x16x32_bf16(a0, b0, acc00, 0, 0, 0);
        acc01 = __builtin_amdgcn_mfma_f32_16x16x32_bf16(a1, b0, acc01, 0, 0, 0);
        acc10 = __builtin_amdgcn_mfma_f32_16x16x32_bf16(a0, b1, acc10, 0, 0, 0);
        acc11 = __builtin_amdgcn_mfma_f32_16x16x32_bf16(a1, b1, acc11, 0, 0, 0);
    }

    int col0 = y * 128 + wave * 32 + lr;
    #pragma unroll
    for (int m = 0; m < 2; ++m) {
        #pragma unroll
        for (int j = 0; j < 4; ++j) {
            int tl = m * 16 + jrow + j;
            float w = s_w[tl];
            if (w == 0.f) continue;
            float* orow = out + (size_t)s_tok[tl] * DDIM;
            float v0 = m ? acc01[j] : acc00[j];
            float v1 = m ? acc11[j] : acc10[j];
            atomicAdd(orow + col0,      w * v0);
            atomicAdd(orow + col0 + 16, w * v1);
        }
    }
}

__global__ __launch_bounds__(64) void aux_kernel(const int* counts, const float* p_sum,
                                                 float* out_aux) {
    if (threadIdx.x == 0) {
        float a = 0.f;
        for (int e = 0; e < 16; ++e) a += (float)counts[e] * p_sum[e];
        out_aux[0] = a * 16.f / ((float)NTOK * (float)NTOK);
    }
}

extern "C" void kernel_launch(void* const* d_in, const int* in_sizes, int n_in,
                              void* d_out, int out_size, void* d_ws, size_t ws_size,
                              hipStream_t stream) {
    const float* x      = (const float*)d_in[0];
    const float* gate_w = (const float*)d_in[1];
    const float* sg_w   = (const float*)d_in[2];
    const float* su_w   = (const float*)d_in[3];
    const float* sd_w   = (const float*)d_in[4];
    const float* rg_w   = (const float*)d_in[5];
    const float* ru_w   = (const float*)d_in[6];
    const float* rd_w   = (const float*)d_in[7];
    float* out = (float*)d_out;

    char* ws = (char*)d_ws;
    int*   counts = (int*)(ws + 0);
    int*   cursor = (int*)(ws + 64);
    int*   offs   = (int*)(ws + 128);
    float* p_sum  = (float*)(ws + 256);
    int*   n_rt   = (int*)(ws + 320);
    int*   topk_i = (int*)(ws + 512);
    float* topk_w = (float*)(ws + 16896);
    int*   perm_t = (int*)(ws + 33280);
    float* perm_w = (float*)(ws + 49664);
    int*   tile_e = (int*)(ws + 66048);
    int*   tile_m = (int*)(ws + 66688);
    unsigned short* xb  = (unsigned short*)(ws + WS_XB);
    unsigned short* w1f = (unsigned short*)(ws + WS_W1F);
    unsigned short* wdf = (unsigned short*)(ws + WS_WDF);
    unsigned short* hbuf= (unsigned short*)(ws + WS_H);

    // zero out (tokens*DDIM floats = 1,572,864 = 393,216 float4) + init scalars.
    // aux element (out[1572864]) is unconditionally overwritten by aux_kernel.
    zero_init_kernel<<<1536, 256, 0, stream>>>(
        (float4*)out, NTOK * DDIM / 4, counts, cursor, offs, p_sum);

    conv_x_kernel<<<768, 256, 0, stream>>>(x, xb);
    conv_w1f_kernel<<<dim3(288, 17), 256, 0, stream>>>(rg_w, ru_w, sg_w, su_w, w1f);
    conv_wdf_kernel<<<dim3(144, 17), 256, 0, stream>>>(rd_w, sd_w, wdf);

    gate_kernel<<<NTOK / 4, 256, 0, stream>>>(x, gate_w, topk_i, topk_w, counts, p_sum);
    offsets_kernel<<<1, 64, 0, stream>>>(counts, offs, tile_e, tile_m, n_rt);
    scatter_kernel<<<NTOK / 256, 256, 0, stream>>>(topk_i, topk_w, offs, cursor, perm_t, perm_w);

    p1_kernel<<<dim3(NSHT + NRT_MAX, 6), 256, 0, stream>>>(
        xb, w1f, perm_t, offs, counts, tile_e, tile_m, n_rt, hbuf);
    p2_kernel<<<dim3(NSHT + NRT_MAX, 6), 256, 0, stream>>>(
        hbuf, wdf, perm_t, perm_w, offs, counts, tile_e, tile_m, n_rt, out);

    aux_kernel<<<1, 64, 0, stream>>>(counts, p_sum, out + (size_t)NTOK * DDIM);
}

// Round 5
// 110.969 us; speedup vs baseline: 9.4802x; 1.2421x over previous
//
#include <hip/hip_runtime.h>
#include <math.h>

#define NTOK 2048
#define DDIM 768
#define IDIM 384
#define NEXP 16
#define XS_LD 776        // 768 + 8 pad (ushorts)
#define HS_LD 392        // 384 + 8 pad (ushorts)
#define NRT_MAX 144      // max routed m-tiles (4096/32 + 15 partials)
#define NSHT 64          // shared m-tiles (2048/32)
#define NWORK ((NSHT + NRT_MAX) * 6)   // 1248 = 8 * 156
#define CHUNK (NWORK / 8)              // 156

typedef __attribute__((ext_vector_type(8))) short short8;   // 8 bf16 = 4 VGPR
typedef __attribute__((ext_vector_type(4))) float f32x4;    // MFMA C/D

__device__ __forceinline__ unsigned short f2bf(float f) {
    unsigned int u = __float_as_uint(f);
    unsigned int r = (u + 0x7fffu + ((u >> 16) & 1u)) >> 16;   // RNE
    return (unsigned short)r;
}

// ---------------- workspace layout (bytes) ----------------
// 0    counts[16] | 64 cursor[16] | 128 offs[17] | 256 p_sum[16] | 320 n_rt
// 512  topk_i | 16896 topk_w | 33280 perm_t | 49664 perm_w
// 66048 tile_e[160] | 66688 tile_m[160]
#define WS_XB   1048576u                     // x bf16: 2048*768*2 = 3,145,728
#define WS_W1F  4194304u                     // w1 frag-major: 17*768*768*2 = 20,054,016
#define WS_WDF  24248320u                    // wd frag-major: 17*768*384*2 = 10,027,008
#define WS_H    34275328u                    // h: 6176*384*2 = 4,743,168 (end 39,018,496)

// zero d_out (float4-vectorized) + init control scalars (block 0).
__global__ __launch_bounds__(256) void zero_init_kernel(
    float4* __restrict__ out4, int n4,
    int* counts, int* cursor, int* offs, float* p_sum) {
    int i = blockIdx.x * 256 + threadIdx.x;
    if (i < n4) out4[i] = make_float4(0.f, 0.f, 0.f, 0.f);
    if (blockIdx.x == 0) {
        int t = threadIdx.x;
        if (t < 16) { counts[t] = 0; cursor[t] = 0; p_sum[t] = 0.f; }
        if (t < 17) offs[t] = 0;
    }
}

// All fp32->bf16 conversions in one launch.
// blocks [0,768): x plain; [768,5664): w1 frag-major; [5664,8112): wd frag-major.
__global__ __launch_bounds__(256) void conv_all_kernel(
    const float* __restrict__ x,
    const float* __restrict__ rgw, const float* __restrict__ ruw,
    const float* __restrict__ sgw, const float* __restrict__ suw,
    const float* __restrict__ rdw, const float* __restrict__ sdw,
    unsigned short* __restrict__ xb, unsigned short* __restrict__ w1f,
    unsigned short* __restrict__ wdf) {
    int b = blockIdx.x, tid = threadIdx.x;
    const float* s;
    unsigned short* dst;
    if (b < 768) {
        int i = b * 256 + tid;                       // 0..196607 chunks of 8
        s = x + (size_t)i * 8;
        dst = xb + (size_t)i * 8;
    } else if (b < 768 + 288 * 17) {
        int bb = b - 768;
        int E = bb / 288, bx = bb % 288;
        const float* gsrc = (E == 16) ? sgw : rgw + (size_t)E * (IDIM * DDIM);
        const float* usrc = (E == 16) ? suw : ruw + (size_t)E * (IDIM * DDIM);
        int i = bx * 256 + tid;                      // 0..73727
        int lane = i & 63;
        int fi = i >> 6;                             // 0..1151
        int ks = fi % 24, rg = fi / 24;              // rg 0..47
        int b16 = rg >> 1, gu = rg & 1;
        s = (gu ? usrc : gsrc)
          + (size_t)(b16 * 16 + (lane & 15)) * DDIM + ks * 32 + (lane >> 4) * 8;
        dst = w1f + (size_t)E * (DDIM * DDIM) + (size_t)i * 8;
    } else {
        int bb = b - (768 + 288 * 17);
        int E = bb / 144, bx = bb % 144;
        const float* src = (E == 16) ? sdw : rdw + (size_t)E * (DDIM * IDIM);
        int i = bx * 256 + tid;                      // 0..36863
        int lane = i & 63;
        int fi = i >> 6;                             // 0..575
        int ks = fi % 12, cg = fi / 12;              // cg 0..47
        s = src + (size_t)(cg * 16 + (lane & 15)) * IDIM + ks * 32 + (lane >> 4) * 8;
        dst = wdf + (size_t)E * (DDIM * IDIM) + (size_t)i * 8;
    }
    float4 v0 = *(const float4*)s, v1 = *(const float4*)(s + 4);
    short8 o;
    o[0]=f2bf(v0.x); o[1]=f2bf(v0.y); o[2]=f2bf(v0.z); o[3]=f2bf(v0.w);
    o[4]=f2bf(v1.x); o[5]=f2bf(v1.y); o[6]=f2bf(v1.z); o[7]=f2bf(v1.w);
    *(short8*)dst = o;
}

__global__ __launch_bounds__(256) void gate_kernel(
    const float* __restrict__ x, const float* __restrict__ gate_w,
    int* __restrict__ topk_i, float* __restrict__ topk_w,
    int* __restrict__ counts, float* __restrict__ p_sum) {
    __shared__ float p_blk[16];
    __shared__ int   c_blk[16];
    int tid = threadIdx.x;
    if (tid < 16) { p_blk[tid] = 0.f; c_blk[tid] = 0; }
    __syncthreads();

    int wave = tid >> 6, lane = tid & 63;
    int n = blockIdx.x * 4 + wave;
    int e = lane >> 2, q = lane & 3;
    const float4* xr = (const float4*)(x + (size_t)n * DDIM);
    const float4* wr = (const float4*)(gate_w + (size_t)e * DDIM);
    float s = 0.f;
    #pragma unroll 4
    for (int k = q * 48; k < q * 48 + 48; ++k) {
        float4 a = xr[k], b = wr[k];
        s += a.x * b.x + a.y * b.y + a.z * b.z + a.w * b.w;
    }
    s += __shfl_xor(s, 1);
    s += __shfl_xor(s, 2);
    float logit = s * 2.5f;

    float l[16];
    #pragma unroll
    for (int j = 0; j < 16; ++j) l[j] = __shfl(logit, j * 4);

    float m = l[0];
    #pragma unroll
    for (int j = 1; j < 16; ++j) m = fmaxf(m, l[j]);
    float sum = 0.f, sc[16];
    #pragma unroll
    for (int j = 0; j < 16; ++j) { sc[j] = __expf(l[j] - m); sum += sc[j]; }
    float inv = 1.f / sum;
    #pragma unroll
    for (int j = 0; j < 16; ++j) sc[j] *= inv;

    float b0 = -1.f; int i0 = 0;
    #pragma unroll
    for (int j = 0; j < 16; ++j) if (sc[j] > b0) { b0 = sc[j]; i0 = j; }
    float b1 = -1.f; int i1 = 0;
    #pragma unroll
    for (int j = 0; j < 16; ++j) if (j != i0 && sc[j] > b1) { b1 = sc[j]; i1 = j; }
    float rs = 1.f / (b0 + b1);

    if (lane == 0) {
        topk_i[n * 2] = i0; topk_i[n * 2 + 1] = i1;
        topk_w[n * 2] = b0 * rs; topk_w[n * 2 + 1] = b1 * rs;
        atomicAdd(&c_blk[i0], 1); atomicAdd(&c_blk[i1], 1);
        #pragma unroll
        for (int j = 0; j < 16; ++j) atomicAdd(&p_blk[j], sc[j]);
    }
    __syncthreads();
    if (tid < 16) {
        atomicAdd(&p_sum[tid], p_blk[tid]);
        atomicAdd(&counts[tid], c_blk[tid]);
    }
}

// Fused: prefix offsets + (expert, m-tile) worklist + aux loss + token scatter.
// Single block, 256 threads, LDS cursors.
__global__ __launch_bounds__(256) void route_kernel(
    const int* __restrict__ counts, const float* __restrict__ p_sum,
    const int* __restrict__ topk_i, const float* __restrict__ topk_w,
    int* __restrict__ offs, int* __restrict__ perm_t, float* __restrict__ perm_w,
    int* __restrict__ tile_e, int* __restrict__ tile_m, int* __restrict__ n_rt,
    float* __restrict__ out_aux) {
    __shared__ int s_off[17];
    __shared__ int s_cur[16];
    int tid = threadIdx.x;
    if (tid < 16) s_cur[tid] = 0;
    if (tid == 0) {
        int acc = 0, n = 0;
        float a = 0.f;
        for (int e = 0; e < 16; ++e) {
            int c = counts[e];
            s_off[e] = acc; offs[e] = acc;
            a += (float)c * p_sum[e];
            for (int t = 0; t < c; t += 32) { tile_e[n] = e; tile_m[n] = acc + t; ++n; }
            acc += c;
        }
        s_off[16] = acc; offs[16] = acc;
        *n_rt = n;
        out_aux[0] = a * 16.f / ((float)NTOK * (float)NTOK);
    }
    __syncthreads();
    for (int n0 = tid; n0 < NTOK; n0 += 256) {
        #pragma unroll
        for (int k = 0; k < 2; ++k) {
            int e = topk_i[n0 * 2 + k];
            int pos = atomicAdd(&s_cur[e], 1);
            int s = s_off[e] + pos;
            perm_t[s] = n0;
            perm_w[s] = topk_w[n0 * 2 + k];
        }
    }
}

// XCD-bijective swizzle: 1248 blocks, lid%8 = XCD -> each XCD gets 156
// consecutive work items (26 tiles x 6 y) => same-expert weight reads L2-hit.
__device__ __forceinline__ void swz_decode(int lid, int& bx, int& y) {
    int wid = (lid & 7) * CHUNK + (lid >> 3);
    bx = wid / 6;
    y = wid - bx * 6;
}

// phase 1: g,u GEMM + fused SiLU -> h.  grid NWORK, 256 thr.
__global__ __launch_bounds__(256, 3) void p1_kernel(
    const unsigned short* __restrict__ xb, const unsigned short* __restrict__ w1f,
    const int* __restrict__ perm_t,
    const int* __restrict__ offs, const int* __restrict__ counts,
    const int* __restrict__ tile_e, const int* __restrict__ tile_m,
    const int* __restrict__ n_rt,
    unsigned short* __restrict__ h) {
    __shared__ unsigned short xs[32 * XS_LD];   // 49,664 B
    __shared__ int s_tok[32];
    __shared__ int s_hrow[32];

    int tid = threadIdx.x;
    int bx, y;
    swz_decode(blockIdx.x, bx, y);
    int e;
    if (bx < NSHT) {
        e = 16;
        if (tid < 32) { int t = bx * 32 + tid; s_tok[tid] = t; s_hrow[tid] = 4096 + t; }
    } else {
        int r = bx - NSHT;
        if (r >= *n_rt) return;
        e = tile_e[r];
        int m0 = tile_m[r];
        int end = offs[e] + counts[e];
        if (tid < 32) {
            int slot = m0 + tid;
            bool v = slot < end;
            s_tok[tid]  = v ? perm_t[slot] : 0;
            s_hrow[tid] = v ? slot : 6144 + tid;   // dummy rows, never read
        }
    }
    __syncthreads();

    for (int c = tid; c < 32 * 96; c += 256) {
        int row = c / 96, off = (c - row * 96) * 8;
        *(short8*)(xs + row * XS_LD + off) =
            *(const short8*)(xb + (size_t)s_tok[row] * DDIM + off);
    }
    __syncthreads();

    int lane = tid & 63, wave = tid >> 6;
    int lr = lane & 15, kg = (lane >> 4) * 8, jrow = (lane >> 4) * 4;

    const unsigned short* pg = w1f + ((((size_t)e * 48 + (y * 8 + wave * 2    )) * 24) * 64 + lane) * 8;
    const unsigned short* pu = w1f + ((((size_t)e * 48 + (y * 8 + wave * 2 + 1)) * 24) * 64 + lane) * 8;

    f32x4 accg0 = (f32x4)0.f, accg1 = (f32x4)0.f, accu0 = (f32x4)0.f, accu1 = (f32x4)0.f;
    for (int ks = 0; ks < 24; ++ks) {
        short8 a0 = *(const short8*)(xs + lr * XS_LD + ks * 32 + kg);
        short8 a1 = *(const short8*)(xs + (16 + lr) * XS_LD + ks * 32 + kg);
        short8 bg = *(const short8*)(pg + (size_t)ks * 512);
        short8 bu = *(const short8*)(pu + (size_t)ks * 512);
        accg0 = __builtin_amdgcn_mfma_f32_16x16x32_bf16(a0, bg, accg0, 0, 0, 0);
        accg1 = __builtin_amdgcn_mfma_f32_16x16x32_bf16(a1, bg, accg1, 0, 0, 0);
        accu0 = __builtin_amdgcn_mfma_f32_16x16x32_bf16(a0, bu, accu0, 0, 0, 0);
        accu1 = __builtin_amdgcn_mfma_f32_16x16x32_bf16(a1, bu, accu1, 0, 0, 0);
    }

    int colg = y * 64 + wave * 16 + lr;
    #pragma unroll
    for (int m = 0; m < 2; ++m) {
        #pragma unroll
        for (int j = 0; j < 4; ++j) {
            int tl = m * 16 + jrow + j;
            float g = m ? accg1[j] : accg0[j];
            float u = m ? accu1[j] : accu0[j];
            float hv = g / (1.f + __expf(-g)) * u;
            h[(size_t)s_hrow[tl] * IDIM + colg] = f2bf(hv);
        }
    }
}

// phase 2: out GEMM + weighted atomic accumulate. grid NWORK, 256 thr.
__global__ __launch_bounds__(256, 4) void p2_kernel(
    const unsigned short* __restrict__ h, const unsigned short* __restrict__ wdf,
    const int* __restrict__ perm_t, const float* __restrict__ perm_w,
    const int* __restrict__ offs, const int* __restrict__ counts,
    const int* __restrict__ tile_e, const int* __restrict__ tile_m,
    const int* __restrict__ n_rt,
    float* __restrict__ out) {
    __shared__ unsigned short hs[32 * HS_LD];   // 25,088 B
    __shared__ int   s_tok[32];
    __shared__ float s_w[32];
    __shared__ int   s_arow[32];

    int tid = threadIdx.x;
    int bx, y;
    swz_decode(blockIdx.x, bx, y);
    int e;
    if (bx < NSHT) {
        e = 16;
        if (tid < 32) {
            int t = bx * 32 + tid;
            s_tok[tid] = t; s_w[tid] = 1.f; s_arow[tid] = 4096 + t;
        }
    } else {
        int r = bx - NSHT;
        if (r >= *n_rt) return;
        e = tile_e[r];
        int m0 = tile_m[r];
        int end = offs[e] + counts[e];
        if (tid < 32) {
            int slot = m0 + tid;
            bool v = slot < end;
            s_tok[tid]  = v ? perm_t[slot] : 0;
            s_w[tid]    = v ? perm_w[slot] : 0.f;
            s_arow[tid] = v ? slot : offs[e];      // clamp: always-valid finite row
        }
    }
    __syncthreads();

    for (int c = tid; c < 32 * 48; c += 256) {
        int row = c / 48, off = (c - row * 48) * 8;
        *(short8*)(hs + row * HS_LD + off) =
            *(const short8*)(h + (size_t)s_arow[row] * IDIM + off);
    }
    __syncthreads();

    int lane = tid & 63, wave = tid >> 6;
    int lr = lane & 15, kg = (lane >> 4) * 8, jrow = (lane >> 4) * 4;

    const unsigned short* p0 = wdf + ((((size_t)e * 48 + (y * 8 + wave * 2    )) * 12) * 64 + lane) * 8;
    const unsigned short* p1 = wdf + ((((size_t)e * 48 + (y * 8 + wave * 2 + 1)) * 12) * 64 + lane) * 8;

    f32x4 acc00 = (f32x4)0.f, acc01 = (f32x4)0.f, acc10 = (f32x4)0.f, acc11 = (f32x4)0.f;
    for (int ks = 0; ks < 12; ++ks) {
        short8 a0 = *(const short8*)(hs + lr * HS_LD + ks * 32 + kg);
        short8 a1 = *(const short8*)(hs + (16 + lr) * HS_LD + ks * 32 + kg);
        short8 b0 = *(const short8*)(p0 + (size_t)ks * 512);
        short8 b1 = *(const short8*)(p1 + (size_t)ks * 512);
        acc00 = __builtin_amdgcn_mfma_f32_16x16x32_bf16(a0, b0, acc00, 0, 0, 0);
        acc01 = __builtin_amdgcn_mfma_f32_16x16x32_bf16(a1, b0, acc01, 0, 0, 0);
        acc10 = __builtin_amdgcn_mfma_f32_16x16x32_bf16(a0, b1, acc10, 0, 0, 0);
        acc11 = __builtin_amdgcn_mfma_f32_16x16x32_bf16(a1, b1, acc11, 0, 0, 0);
    }

    int col0 = y * 128 + wave * 32 + lr;
    #pragma unroll
    for (int m = 0; m < 2; ++m) {
        #pragma unroll
        for (int j = 0; j < 4; ++j) {
            int tl = m * 16 + jrow + j;
            float w = s_w[tl];
            if (w == 0.f) continue;
            float* orow = out + (size_t)s_tok[tl] * DDIM;
            float v0 = m ? acc01[j] : acc00[j];
            float v1 = m ? acc11[j] : acc10[j];
            atomicAdd(orow + col0,      w * v0);
            atomicAdd(orow + col0 + 16, w * v1);
        }
    }
}

extern "C" void kernel_launch(void* const* d_in, const int* in_sizes, int n_in,
                              void* d_out, int out_size, void* d_ws, size_t ws_size,
                              hipStream_t stream) {
    const float* x      = (const float*)d_in[0];
    const float* gate_w = (const float*)d_in[1];
    const float* sg_w   = (const float*)d_in[2];
    const float* su_w   = (const float*)d_in[3];
    const float* sd_w   = (const float*)d_in[4];
    const float* rg_w   = (const float*)d_in[5];
    const float* ru_w   = (const float*)d_in[6];
    const float* rd_w   = (const float*)d_in[7];
    float* out = (float*)d_out;

    char* ws = (char*)d_ws;
    int*   counts = (int*)(ws + 0);
    int*   cursor = (int*)(ws + 64);
    int*   offs   = (int*)(ws + 128);
    float* p_sum  = (float*)(ws + 256);
    int*   n_rt   = (int*)(ws + 320);
    int*   topk_i = (int*)(ws + 512);
    float* topk_w = (float*)(ws + 16896);
    int*   perm_t = (int*)(ws + 33280);
    float* perm_w = (float*)(ws + 49664);
    int*   tile_e = (int*)(ws + 66048);
    int*   tile_m = (int*)(ws + 66688);
    unsigned short* xb  = (unsigned short*)(ws + WS_XB);
    unsigned short* w1f = (unsigned short*)(ws + WS_W1F);
    unsigned short* wdf = (unsigned short*)(ws + WS_WDF);
    unsigned short* hbuf= (unsigned short*)(ws + WS_H);

    zero_init_kernel<<<1536, 256, 0, stream>>>(
        (float4*)out, NTOK * DDIM / 4, counts, cursor, offs, p_sum);

    conv_all_kernel<<<768 + 288 * 17 + 144 * 17, 256, 0, stream>>>(
        x, rg_w, ru_w, sg_w, su_w, rd_w, sd_w, xb, w1f, wdf);

    gate_kernel<<<NTOK / 4, 256, 0, stream>>>(x, gate_w, topk_i, topk_w, counts, p_sum);

    route_kernel<<<1, 256, 0, stream>>>(counts, p_sum, topk_i, topk_w,
                                        offs, perm_t, perm_w, tile_e, tile_m, n_rt,
                                        out + (size_t)NTOK * DDIM);

    p1_kernel<<<NWORK, 256, 0, stream>>>(
        xb, w1f, perm_t, offs, counts, tile_e, tile_m, n_rt, hbuf);
    p2_kernel<<<NWORK, 256, 0, stream>>>(
        hbuf, wdf, perm_t, perm_w, offs, counts, tile_e, tile_m, n_rt, out);
}